// Round 1
// 1030.897 us; speedup vs baseline: 1.0369x; 1.0369x over previous
//
#include <hip/hip_runtime.h>
#include <math.h>

#define TPB 256
#define NCAT 8
#define CAP 512            // candidate buffer; E[count]=68 for N(0,1) at TAU=3
#define TAU 3.0f           // P(X>3)=1.35e-3 -> ~68 candidates/row; P(<5)~1e-25
#define LOG2E  1.44269504088896f
#define LN2    0.69314718055994f
#define SHIFT  32.0f       // sum = 2^-32 * sum(e^v): overflow-safe to logit ~110

// One block per row. Hot loop: pure streaming sum-of-exp + threshold filter.
// Exact top-5 recovered from a tiny LDS candidate list; input-robust fallback
// (per-thread insertion top-5) covers non-N(0,1) data (e.g. poison fills).
__global__ __launch_bounds__(TPB) void hcl_row_kernel(
    const float* __restrict__ logits,
    const int*   __restrict__ labels,
    const int*   __restrict__ cat_labels,
    const int*   __restrict__ cmd_to_cat,
    float*       __restrict__ row_loss,
    int V)
{
    const int row  = blockIdx.x;
    const int tid  = threadIdx.x;
    const int lane = tid & 63;
    const int wave = tid >> 6;
    const float* __restrict__ rl = logits + (size_t)row * (size_t)V;

    __shared__ float cand_v[CAP];
    __shared__ int   cand_i[CAP];
    __shared__ int   s_cnt;
    __shared__ float sh_s[TPB/64];
    __shared__ float s_top_v[5];
    __shared__ int   s_top_i[5];
    __shared__ int   s_c2c[64];
    // fallback merge scratch
    __shared__ float sh_cv[TPB/64];
    __shared__ int   sh_ci[TPB/64];
    __shared__ float sh_bv;
    __shared__ int   sh_bi;

    if (tid == 0) s_cnt = 0;
    if (tid < 64) s_c2c[tid] = cmd_to_cat[tid];

    // Prefetch epilogue scalars now; latency hides under the streaming loop.
    int lab = 0, clab = 0; float tgt = 0.0f;
    if (tid == 0) { lab = labels[row]; clab = cat_labels[row]; tgt = rl[lab]; }
    __syncthreads();

    // Row base is only 4B-aligned (V % 4 == 1): peel to 16B, float4 body, tail.
    const int mis = (int)(((size_t)rl >> 2) & 3);
    const int pre = (4 - mis) & 3;
    const int nb  = (V - pre) >> 2;
    const float4* __restrict__ body = (const float4*)(rl + pre);

    float a0=0.f,a1=0.f,a2=0.f,a3=0.f,a4=0.f,a5=0.f,a6=0.f,a7=0.f;

#define APPEND(val, gidx) do {                                               \
        int _s = atomicAdd(&s_cnt, 1);                                       \
        if (_s < CAP) { cand_v[_s] = (val); cand_i[_s] = (gidx); }           \
    } while (0)

    int i = tid;
    for (; i + TPB < nb; i += 2*TPB) {
        float4 x = body[i];
        float4 y = body[i + TPB];
        a0 += exp2f(__builtin_fmaf(x.x, LOG2E, -SHIFT));
        a1 += exp2f(__builtin_fmaf(x.y, LOG2E, -SHIFT));
        a2 += exp2f(__builtin_fmaf(x.z, LOG2E, -SHIFT));
        a3 += exp2f(__builtin_fmaf(x.w, LOG2E, -SHIFT));
        a4 += exp2f(__builtin_fmaf(y.x, LOG2E, -SHIFT));
        a5 += exp2f(__builtin_fmaf(y.y, LOG2E, -SHIFT));
        a6 += exp2f(__builtin_fmaf(y.z, LOG2E, -SHIFT));
        a7 += exp2f(__builtin_fmaf(y.w, LOG2E, -SHIFT));
        float mx = fmaxf(fmaxf(fmaxf(x.x, x.y), fmaxf(x.z, x.w)),
                         fmaxf(fmaxf(y.x, y.y), fmaxf(y.z, y.w)));
        if (__builtin_expect(mx > TAU, 0)) {
            int gx = pre + 4 * i;
            int gy = pre + 4 * (i + TPB);
            if (x.x > TAU) APPEND(x.x, gx);
            if (x.y > TAU) APPEND(x.y, gx + 1);
            if (x.z > TAU) APPEND(x.z, gx + 2);
            if (x.w > TAU) APPEND(x.w, gx + 3);
            if (y.x > TAU) APPEND(y.x, gy);
            if (y.y > TAU) APPEND(y.y, gy + 1);
            if (y.z > TAU) APPEND(y.z, gy + 2);
            if (y.w > TAU) APPEND(y.w, gy + 3);
        }
    }
    for (; i < nb; i += TPB) {
        float4 x = body[i];
        a0 += exp2f(__builtin_fmaf(x.x, LOG2E, -SHIFT));
        a1 += exp2f(__builtin_fmaf(x.y, LOG2E, -SHIFT));
        a2 += exp2f(__builtin_fmaf(x.z, LOG2E, -SHIFT));
        a3 += exp2f(__builtin_fmaf(x.w, LOG2E, -SHIFT));
        float mx = fmaxf(fmaxf(x.x, x.y), fmaxf(x.z, x.w));
        if (__builtin_expect(mx > TAU, 0)) {
            int gx = pre + 4 * i;
            if (x.x > TAU) APPEND(x.x, gx);
            if (x.y > TAU) APPEND(x.y, gx + 1);
            if (x.z > TAU) APPEND(x.z, gx + 2);
            if (x.w > TAU) APPEND(x.w, gx + 3);
        }
    }
    if (tid < pre) {
        float v = rl[tid];
        a0 += exp2f(__builtin_fmaf(v, LOG2E, -SHIFT));
        if (v > TAU) APPEND(v, tid);
    }
    for (int g = pre + 4 * nb + tid; g < V; g += TPB) {
        float v = rl[g];
        a0 += exp2f(__builtin_fmaf(v, LOG2E, -SHIFT));
        if (v > TAU) APPEND(v, g);
    }
#undef APPEND

    // ---- wave + block reduce of sum-of-exp ----
    float s = ((a0 + a1) + (a2 + a3)) + ((a4 + a5) + (a6 + a7));
    #pragma unroll
    for (int off = 32; off > 0; off >>= 1) s += __shfl_down(s, off);
    if (lane == 0) sh_s[wave] = s;
    __syncthreads();           // also publishes cand_* and s_cnt

    const int cnt = s_cnt;     // block-uniform
    if (cnt < 5 || cnt > CAP) {
        // ---- exact fallback (never taken for N(0,1) inputs) ----
        float v0=-INFINITY,v1=-INFINITY,v2=-INFINITY,v3=-INFINITY,v4=-INFINITY;
        int   i0=0, i1=0, i2=0, i3=0, i4=0;
#define INSERT(val, gidx) do {                                               \
        v4 = (val); i4 = (gidx);                                             \
        if (v4 > v3) { float t=v3; v3=v4; v4=t; int u=i3; i3=i4; i4=u; }     \
        if (v3 > v2) { float t=v2; v2=v3; v3=t; int u=i2; i2=i3; i3=u; }     \
        if (v2 > v1) { float t=v1; v1=v2; v2=t; int u=i1; i1=i2; i2=u; }     \
        if (v1 > v0) { float t=v0; v0=v1; v1=t; int u=i0; i0=i1; i1=u; }     \
    } while (0)
        for (int g = tid; g < V; g += TPB) {
            float v = rl[g];
            if (v > v4) INSERT(v, g);
        }
#undef INSERT
        #pragma unroll
        for (int r = 0; r < 5; ++r) {
            float cv = v0; int ci = i0;
            #pragma unroll
            for (int off = 32; off > 0; off >>= 1) {
                float ov = __shfl_down(cv, off);
                int   oi = __shfl_down(ci, off);
                if (ov > cv || (ov == cv && oi < ci)) { cv = ov; ci = oi; }
            }
            if (lane == 0) { sh_cv[wave] = cv; sh_ci[wave] = ci; }
            __syncthreads();
            if (tid == 0) {
                float bv = sh_cv[0]; int bi = sh_ci[0];
                #pragma unroll
                for (int w = 1; w < TPB/64; ++w) {
                    float ov = sh_cv[w]; int oi = sh_ci[w];
                    if (ov > bv || (ov == bv && oi < bi)) { bv = ov; bi = oi; }
                }
                sh_bv = bv; sh_bi = bi;
                s_top_v[r] = bv; s_top_i[r] = bi;
            }
            __syncthreads();
            if (v0 == sh_bv && i0 == sh_bi) {
                v0=v1; i0=i1; v1=v2; i1=i2; v2=v3; i2=i3; v3=v4; i3=i4;
                v4=-INFINITY; i4=0;
            }
        }
    } else {
        // ---- top-5 from candidate list: wave 0, 5 argmax rounds ----
        for (int r = 0; r < 5; ++r) {
            if (wave == 0) {
                float cv = -INFINITY; int ci = 0x7fffffff; int cs = 0;
                for (int j = lane; j < cnt; j += 64) {
                    float v = cand_v[j]; int ix = cand_i[j];
                    if (v > cv || (v == cv && ix < ci)) { cv = v; ci = ix; cs = j; }
                }
                #pragma unroll
                for (int off = 32; off > 0; off >>= 1) {
                    float ov = __shfl_down(cv, off);
                    int   oi = __shfl_down(ci, off);
                    int   os = __shfl_down(cs, off);
                    if (ov > cv || (ov == cv && oi < ci)) { cv = ov; ci = oi; cs = os; }
                }
                if (lane == 0) {
                    s_top_v[r] = cv; s_top_i[r] = ci;
                    cand_v[cs] = -INFINITY;   // pop winner
                }
            }
            __syncthreads();
        }
    }

    if (tid == 0) {
        float fs = 0.0f;
        #pragma unroll
        for (int w = 0; w < TPB/64; ++w) fs += sh_s[w];
        // sum = 2^-SHIFT * sum(e^v)  =>  lse = (log2(sum) + SHIFT) * ln2
        float lse = (log2f(fs) + SHIFT) * LN2;
        float nll_cmd = lse - tgt;

        float cl[NCAT];
        #pragma unroll
        for (int c = 0; c < NCAT; ++c) cl[c] = 0.0f;
        #pragma unroll
        for (int r = 0; r < 5; ++r) {
            int c = s_c2c[s_top_i[r] & 63];   // idx % 64 (TOTAL_CMDS = 64)
            float v = s_top_v[r];
            #pragma unroll
            for (int k = 0; k < NCAT; ++k)    // static-index scatter
                cl[k] += (k == c) ? v : 0.0f;
        }
        float mc = cl[0];
        #pragma unroll
        for (int c = 1; c < NCAT; ++c) mc = fmaxf(mc, cl[c]);
        float se = 0.0f;
        #pragma unroll
        for (int c = 0; c < NCAT; ++c) se += __expf(cl[c] - mc);
        float lsec = mc + __logf(se);

        float t2 = 0.0f;
        #pragma unroll
        for (int c = 0; c < NCAT; ++c) t2 += (c == clab) ? cl[c] : 0.0f;
        float nll_cat = lsec - t2;

        row_loss[row] = 0.6f * nll_cmd + 0.4f * nll_cat;
    }
}

__global__ __launch_bounds__(TPB) void hcl_reduce_kernel(
    const float* __restrict__ row_loss, float* __restrict__ out, int B)
{
    const int tid = threadIdx.x;
    float s = 0.0f;
    for (int i = tid; i < B; i += TPB) s += row_loss[i];
    #pragma unroll
    for (int off = 32; off > 0; off >>= 1) s += __shfl_down(s, off);
    __shared__ float sh[TPB/64];
    const int lane = tid & 63, wave = tid >> 6;
    if (lane == 0) sh[wave] = s;
    __syncthreads();
    if (tid == 0) {
        float t = 0.0f;
        #pragma unroll
        for (int w = 0; w < TPB/64; ++w) t += sh[w];
        out[0] = t / (float)B;
    }
}

extern "C" void kernel_launch(void* const* d_in, const int* in_sizes, int n_in,
                              void* d_out, int out_size, void* d_ws, size_t ws_size,
                              hipStream_t stream) {
    const float* logits     = (const float*)d_in[0];
    const int*   labels     = (const int*)  d_in[1];
    const int*   cat_labels = (const int*)  d_in[2];
    const int*   cmd_to_cat = (const int*)  d_in[3];
    const int B = in_sizes[1];
    const int V = in_sizes[0] / B;
    float* row_loss = (float*)d_ws;   // B floats; fully written by kernel 1

    hcl_row_kernel<<<B, TPB, 0, stream>>>(logits, labels, cat_labels,
                                          cmd_to_cat, row_loss, V);
    hcl_reduce_kernel<<<1, TPB, 0, stream>>>(row_loss, (float*)d_out, B);
}